// Round 16
// baseline (240.048 us; speedup 1.0000x reference)
//
#include <hip/hip_runtime.h>
#include <stdint.h>

#define Bv 8
#define Cv 64
#define Lv 65536
#define TPB 256
#define WCOLS 32                      // cols per wave-tile
#define COLS 256                      // cols per block: 4 waves x 2 tiles x 32
#define BLKS_PER_B (Lv / COLS)        // 256
#define GRID1 (Bv * BLKS_PER_B)       // 2048

// workspace: partials 2*2048 floats (16 KiB) + sb 1024 floats (4 KiB) = 20 KiB

typedef __attribute__((ext_vector_type(8))) short short8;
typedef __attribute__((ext_vector_type(4))) float f32x4;

#define WS 36   // slab row stride (dwords): 144B rows -> 16B-aligned uint4,
                // and (4g)*36 % 32 = 16g -> all hot reads max 2-way (free)

__device__ __forceinline__ uint16_t f2bf(float f) {
    uint32_t u = __float_as_uint(f);
    uint32_t r = u + 0x7FFFu + ((u >> 16) & 1u);   // round-to-nearest-even
    return (uint16_t)(r >> 16);
}
__device__ __forceinline__ uint32_t pack2bf(float lo, float hi) {
    return (uint32_t)f2bf(lo) | ((uint32_t)f2bf(hi) << 16);
}
__device__ __forceinline__ float bf_lo(uint32_t u) { return __uint_as_float(u << 16); }
__device__ __forceinline__ float bf_hi(uint32_t u) { return __uint_as_float(u & 0xFFFF0000u); }

// ---------------------------------------------------------------------------
// Pass 1 (MFMA, wave-autonomous): out = relu(Wf·(x⊙(Wg·s+2bg)) + bf + resid)
// R16 theory: 5 variants pinned at ~171us across occupancy/blocks/pipelining;
// R11's barrier-free spill streams hit 4.04 TB/s and pass3 streams at ~20TB/s
// (L3). The invariant killer = block-wide barrier drains (whole block has 0
// outstanding VMEM at each drain; 2-3 barrier domains/CU -> HBM idles).
// Fix: each wave owns a private 32-col tile end-to-end in its OWN LDS slabs
// -> producer==consumer -> ZERO block barriers in the main loop. 8
// independent wave-streams/CU, desynchronized by construction.
// ---------------------------------------------------------------------------
__global__ void pass1(const float* __restrict__ x, const float* __restrict__ inj0,
                      const float* __restrict__ inj1, const float* __restrict__ resid,
                      const float* __restrict__ gate_w, const float* __restrict__ gate_b,
                      const float* __restrict__ fuse_w, const float* __restrict__ fuse_b,
                      float* __restrict__ out, float* __restrict__ partials)
{
    __shared__ uint32_t w_lds[2][64][WS];      // 18.4 KB (shared, read-only)
    __shared__ uint32_t s_all[4][32 * WS];     // 18.4 KB (per-wave s slabs)
    __shared__ uint32_t x_all[4][32 * WS];     // 18.4 KB (per-wave x slabs)
    __shared__ uint32_t a_all[4][16 * WS];     //  9.2 KB (per-wave acc slabs)
    __shared__ float cinit[2][64];             // [0]=2*gate_b, [1]=fuse_b
    __shared__ float wred[8];

    const int tid  = threadIdx.x;
    const int lane = tid & 63;
    const int w    = tid >> 6;     // wave 0..3
    const int g    = lane >> 4;    // k-group 0..3
    const int ln   = lane & 15;    // 0..15

    const int b    = blockIdx.x >> 8;
    const int lb   = blockIdx.x & 255;
    const int bCL  = b * (Cv * Lv);

    uint32_t* s_slab = s_all[w];
    uint32_t* x_slab = x_all[w];
    uint32_t* a_slab = a_all[w];

    // ---- stage weights + cinit (once; the ONLY producer barrier) ----
    #pragma unroll
    for (int uu = 0; uu < 2; ++uu) {
        const int unit = tid + uu * TPB;       // 512 units
        const int mat  = unit >> 8;            // 0=gate, 1=fuse
        const int m    = (unit >> 2) & 63;
        const int k0   = (unit & 3) << 4;
        const float* wsrc = mat ? fuse_w : gate_w;
        const float4* w4 = reinterpret_cast<const float4*>(wsrc + m * 64 + k0);
        uint32_t* dst = &w_lds[mat][m][k0 >> 1];
        #pragma unroll
        for (int q = 0; q < 4; ++q) {
            const float4 v = w4[q];
            dst[2 * q]     = pack2bf(v.x, v.y);
            dst[2 * q + 1] = pack2bf(v.z, v.w);
        }
    }
    if (tid < 64) {
        cinit[0][tid] = 2.0f * gate_b[tid];
        cinit[1][tid] = fuse_b[tid];
    }
    __syncthreads();

    float lsum = 0.0f, lsq = 0.0f;

    #pragma unroll 1
    for (int t = 0; t < 2; ++t) {
        const int col0w = lb * COLS + w * 64 + t * WCOLS;   // wave's 32 cols

        // ---- stage s = i0+i1+2x AND x (bf16 kpairs) into OWN slabs ----
        // per it: 8 lanes x float4 = 128B rows, 8 row-pairs per instruction
        #pragma unroll
        for (int it = 0; it < 4; ++it) {
            const int kp = 8 * it + (lane >> 3);   // ch pair 0..31
            const int c  = (lane & 7) << 2;        // col 0..28
            const int rA = bCL + (2 * kp) * Lv + col0w + c;
            const int rB = rA + Lv;
            const float4 xA = *reinterpret_cast<const float4*>(x    + rA);
            const float4 aA = *reinterpret_cast<const float4*>(inj0 + rA);
            const float4 bA = *reinterpret_cast<const float4*>(inj1 + rA);
            const float4 xB = *reinterpret_cast<const float4*>(x    + rB);
            const float4 aB = *reinterpret_cast<const float4*>(inj0 + rB);
            const float4 bB = *reinterpret_cast<const float4*>(inj1 + rB);
            uint4 ds, dx;
            ds.x = pack2bf(aA.x + bA.x + 2.0f * xA.x, aB.x + bB.x + 2.0f * xB.x);
            ds.y = pack2bf(aA.y + bA.y + 2.0f * xA.y, aB.y + bB.y + 2.0f * xB.y);
            ds.z = pack2bf(aA.z + bA.z + 2.0f * xA.z, aB.z + bB.z + 2.0f * xB.z);
            ds.w = pack2bf(aA.w + bA.w + 2.0f * xA.w, aB.w + bB.w + 2.0f * xB.w);
            *reinterpret_cast<uint4*>(&s_slab[kp * WS + c]) = ds;
            dx.x = pack2bf(xA.x, xB.x);
            dx.y = pack2bf(xA.y, xB.y);
            dx.z = pack2bf(xA.z, xB.z);
            dx.w = pack2bf(xA.w, xB.w);
            *reinterpret_cast<uint4*>(&x_slab[kp * WS + c]) = dx;
        }
        // no barrier: this wave wrote, this wave reads (waitcnt only)

        // ---- resid prefetch for epilogue chunk 0 (drains under GEMMs) ----
        float4 rp0[4];
        #pragma unroll
        for (int p = 0; p < 4; ++p) {
            const int m = 8 * p + (lane >> 3);
            rp0[p] = *reinterpret_cast<const float4*>(
                &resid[bCL + m * Lv + col0w + ((lane & 7) << 2)]);
        }

        f32x4 D2[4][2];
        #pragma unroll
        for (int oc = 0; oc < 4; ++oc) {
            const float4 cb = *reinterpret_cast<const float4*>(&cinit[1][16 * oc + 4 * g]);
            D2[oc][0][0] = cb.x; D2[oc][0][1] = cb.y;
            D2[oc][0][2] = cb.z; D2[oc][0][3] = cb.w;
            D2[oc][1] = D2[oc][0];
        }

        // ==== two M-phases: gate rows 0-31 then 32-63 ====
        #pragma unroll 1
        for (int ph = 0; ph < 2; ++ph) {
            // ---- GEMM1: D1 = Wg[rows].s + 2bg (full K) ----
            f32x4 D1[2][2];
            #pragma unroll
            for (int o2 = 0; o2 < 2; ++o2) {
                const int oc = 2 * ph + o2;
                const float4 cb = *reinterpret_cast<const float4*>(&cinit[0][16 * oc + 4 * g]);
                D1[o2][0][0] = cb.x; D1[o2][0][1] = cb.y;
                D1[o2][0][2] = cb.z; D1[o2][0][3] = cb.w;
                D1[o2][1] = D1[o2][0];
            }
            #pragma unroll
            for (int nt = 0; nt < 2; ++nt) {
                const int n = ln + 16 * nt;
                uint4 B0, B1;
                B0.x = s_slab[(4 * g + 0) * WS + n];
                B0.y = s_slab[(4 * g + 1) * WS + n];
                B0.z = s_slab[(4 * g + 2) * WS + n];
                B0.w = s_slab[(4 * g + 3) * WS + n];
                B1.x = s_slab[(16 + 4 * g + 0) * WS + n];
                B1.y = s_slab[(16 + 4 * g + 1) * WS + n];
                B1.z = s_slab[(16 + 4 * g + 2) * WS + n];
                B1.w = s_slab[(16 + 4 * g + 3) * WS + n];
                #pragma unroll
                for (int o2 = 0; o2 < 2; ++o2) {
                    const int m = ln + 16 * (2 * ph + o2);
                    const uint4 A0 = *reinterpret_cast<const uint4*>(&w_lds[0][m][4 * g]);
                    const uint4 A1 = *reinterpret_cast<const uint4*>(&w_lds[0][m][16 + 4 * g]);
                    D1[o2][nt] = __builtin_amdgcn_mfma_f32_16x16x32_bf16(
                        __builtin_bit_cast(short8, A0), __builtin_bit_cast(short8, B0),
                        D1[o2][nt], 0, 0, 0);
                    D1[o2][nt] = __builtin_amdgcn_mfma_f32_16x16x32_bf16(
                        __builtin_bit_cast(short8, A1), __builtin_bit_cast(short8, B1),
                        D1[o2][nt], 0, 0, 0);
                }
            }

            // ---- acc = x*g for these 32 ch (x from OWN x_slab) -> a_slab ----
            #pragma unroll
            for (int nt = 0; nt < 2; ++nt) {
                const int n = ln + 16 * nt;
                #pragma unroll
                for (int o2 = 0; o2 < 2; ++o2) {
                    const int kpx = (16 * (2 * ph + o2) + 4 * g) >> 1;  // abs ch pair
                    const uint32_t u0 = x_slab[kpx * WS + n];
                    const uint32_t u1 = x_slab[(kpx + 1) * WS + n];
                    float av[4];
                    av[0] = bf_lo(u0) * D1[o2][nt][0];
                    av[1] = bf_hi(u0) * D1[o2][nt][1];
                    av[2] = bf_lo(u1) * D1[o2][nt][2];
                    av[3] = bf_hi(u1) * D1[o2][nt][3];
                    const int kpA = 8 * o2 + 2 * g;
                    a_slab[kpA * WS + n]       = pack2bf(av[0], av[1]);
                    a_slab[(kpA + 1) * WS + n] = pack2bf(av[2], av[3]);
                }
            }
            // no barrier: wave-local slab

            // ---- GEMM2 partial-K: D2 += Wf[:, kslab] . acc ----
            #pragma unroll
            for (int nt = 0; nt < 2; ++nt) {
                const int n = ln + 16 * nt;
                uint4 Bf;
                Bf.x = a_slab[(4 * g + 0) * WS + n];
                Bf.y = a_slab[(4 * g + 1) * WS + n];
                Bf.z = a_slab[(4 * g + 2) * WS + n];
                Bf.w = a_slab[(4 * g + 3) * WS + n];
                #pragma unroll
                for (int oc = 0; oc < 4; ++oc) {
                    const int m = ln + 16 * oc;
                    const uint4 A2 = *reinterpret_cast<const uint4*>(
                        &w_lds[1][m][16 * ph + 4 * g]);
                    D2[oc][nt] = __builtin_amdgcn_mfma_f32_16x16x32_bf16(
                        __builtin_bit_cast(short8, A2), __builtin_bit_cast(short8, Bf),
                        D2[oc][nt], 0, 0, 0);
                }
            }
        }

        // ---- epilogue (wave-local): 2 chunks of 32 rows via s_slab re-use ----
        {
            float* uf = reinterpret_cast<float*>(s_slab);
            const int rr = lane >> 3;            // 0..7
            const int c4 = (lane & 7) << 2;      // col 0..28
            #pragma unroll 1
            for (int ck = 0; ck < 2; ++ck) {
                // prefetch next chunk's resid while this chunk's frag-write runs
                float4 rp1[4];
                if (ck == 0) {
                    #pragma unroll
                    for (int p = 0; p < 4; ++p) {
                        const int m = 32 + 8 * p + rr;
                        rp1[p] = *reinterpret_cast<const float4*>(
                            &resid[bCL + m * Lv + col0w + c4]);
                    }
                }
                // fragments -> fp32 tile (rows 32ck..32ck+31; in-chunk idx 16o2+4g+j)
                #pragma unroll
                for (int o2 = 0; o2 < 2; ++o2) {
                    const int oc = 2 * ck + o2;
                    #pragma unroll
                    for (int nt = 0; nt < 2; ++nt) {
                        const int n = ln + 16 * nt;
                        #pragma unroll
                        for (int j = 0; j < 4; ++j)
                            uf[(16 * o2 + 4 * g + j) * WS + n] = D2[oc][nt][j];
                    }
                }
                // wave-local read-back: 4 passes x (8 rows x 128B)
                #pragma unroll
                for (int p = 0; p < 4; ++p) {
                    const int r   = 8 * p + rr;
                    const int m   = 32 * ck + r;
                    const int gbm = bCL + m * Lv + col0w + c4;
                    float4 v = *reinterpret_cast<const float4*>(&uf[r * WS + c4]);
                    const float4 rv = rp0[p];
                    v.x = fmaxf(v.x + rv.x, 0.0f);
                    v.y = fmaxf(v.y + rv.y, 0.0f);
                    v.z = fmaxf(v.z + rv.z, 0.0f);
                    v.w = fmaxf(v.w + rv.w, 0.0f);
                    *reinterpret_cast<float4*>(&out[gbm]) = v;
                    lsum += (v.x + v.y) + (v.z + v.w);
                    lsq = fmaf(v.x, v.x, lsq);
                    lsq = fmaf(v.y, v.y, lsq);
                    lsq = fmaf(v.z, v.z, lsq);
                    lsq = fmaf(v.w, v.w, lsq);
                }
                if (ck == 0) {
                    #pragma unroll
                    for (int p = 0; p < 4; ++p) rp0[p] = rp1[p];
                }
            }
        }
    }

    // ---- stats: wave shuffle reduce -> 4 partials -> thread 0 ----
    #pragma unroll
    for (int st = 1; st < 64; st <<= 1) {
        lsum += __shfl_xor(lsum, st);
        lsq  += __shfl_xor(lsq,  st);
    }
    if (lane == 0) { wred[2 * w] = lsum; wred[2 * w + 1] = lsq; }
    __syncthreads();
    if (tid == 0) {
        float s = 0.0f, q = 0.0f;
        #pragma unroll
        for (int i = 0; i < 4; ++i) { s += wred[2 * i]; q += wred[2 * i + 1]; }
        partials[2 * blockIdx.x]     = s;
        partials[2 * blockIdx.x + 1] = q;
    }
}

// ---------------------------------------------------------------------------
// Pass 2: reduce 256 partials per batch -> per-(b,c) scale/bias.
// ---------------------------------------------------------------------------
__global__ __launch_bounds__(256)
void pass2(const float* __restrict__ partials, const float* __restrict__ gn_w,
           const float* __restrict__ gn_b, float* __restrict__ sb)
{
    __shared__ float r1[256], r2[256];
    __shared__ float mean_s, rs_s;
    const int b = blockIdx.x, tid = threadIdx.x;
    r1[tid] = partials[2 * (b * 256 + tid)];
    r2[tid] = partials[2 * (b * 256 + tid) + 1];
    __syncthreads();
    #pragma unroll
    for (int st = 128; st > 0; st >>= 1) {
        if (tid < st) { r1[tid] += r1[tid + st]; r2[tid] += r2[tid + st]; }
        __syncthreads();
    }
    if (tid == 0) {
        const float n = (float)Cv * (float)Lv;
        const float mean = r1[0] / n;
        const float var  = r2[0] / n - mean * mean;
        mean_s = mean;
        rs_s   = rsqrtf(var + 1e-5f);
    }
    __syncthreads();
    if (tid < Cv) {
        const float sc = gn_w[tid] * rs_s;
        sb[b * Cv + tid]           = sc;
        sb[Bv * Cv + b * Cv + tid] = fmaf(-mean_s, sc, gn_b[tid]);
    }
}

// ---------------------------------------------------------------------------
// Pass 3: in-place GroupNorm affine on d_out (float4 vectorized).
// ---------------------------------------------------------------------------
__global__ __launch_bounds__(256)
void pass3(float* __restrict__ out, const float* __restrict__ sb)
{
    const int total4 = (Bv * Cv * Lv) / 4;   // 8388608
    for (int i = blockIdx.x * blockDim.x + threadIdx.x; i < total4;
         i += gridDim.x * blockDim.x) {
        const int row = i >> 14;            // / (L/4): row = b*64 + c
        const float sc = sb[row];
        const float bi = sb[Bv * Cv + row];
        float4 v = reinterpret_cast<float4*>(out)[i];
        v.x = fmaf(v.x, sc, bi);
        v.y = fmaf(v.y, sc, bi);
        v.z = fmaf(v.z, sc, bi);
        v.w = fmaf(v.w, sc, bi);
        reinterpret_cast<float4*>(out)[i] = v;
    }
}

extern "C" void kernel_launch(void* const* d_in, const int* in_sizes, int n_in,
                              void* d_out, int out_size, void* d_ws, size_t ws_size,
                              hipStream_t stream)
{
    const float* x      = (const float*)d_in[0];
    const float* inj0   = (const float*)d_in[1];
    const float* inj1   = (const float*)d_in[2];
    const float* resid  = (const float*)d_in[3];
    const float* gate_w = (const float*)d_in[4];
    const float* gate_b = (const float*)d_in[5];
    const float* fuse_w = (const float*)d_in[6];
    const float* fuse_b = (const float*)d_in[7];
    const float* gn_w   = (const float*)d_in[8];
    const float* gn_b   = (const float*)d_in[9];

    float* out      = (float*)d_out;
    float* ws       = (float*)d_ws;
    float* partials = ws;                 // 2 * 2048 floats = 16 KiB
    float* sb       = ws + 2 * GRID1;     // 2 * 512 floats  =  4 KiB

    hipLaunchKernelGGL(pass1, dim3(GRID1), dim3(TPB), 0, stream,
                       x, inj0, inj1, resid, gate_w, gate_b, fuse_w, fuse_b,
                       out, partials);
    hipLaunchKernelGGL(pass2, dim3(Bv), dim3(256), 0, stream,
                       partials, gn_w, gn_b, sb);
    hipLaunchKernelGGL(pass3, dim3(2048), dim3(256), 0, stream, out, sb);
}

// Round 17
// 184.608 us; speedup vs baseline: 1.3003x; 1.3003x over previous
//
#include <hip/hip_runtime.h>
#include <stdint.h>

#define Bv 8
#define Cv 64
#define Lv 65536
#define TPB 512
#define HALF 128                      // cols per half-tile
#define COLS 256                      // cols per block (2 halves)
#define BLKS_PER_B (Lv / COLS)        // 256
#define GRID1 (Bv * BLKS_PER_B)       // 2048

// workspace: partials 2*2048 floats (16 KiB) + sb 1024 floats (4 KiB) = 20 KiB

typedef __attribute__((ext_vector_type(8))) short short8;
typedef __attribute__((ext_vector_type(4))) float f32x4;

#define SSTRIDE 132   // dwords per row

__device__ __forceinline__ uint16_t f2bf(float f) {
    uint32_t u = __float_as_uint(f);
    uint32_t r = u + 0x7FFFu + ((u >> 16) & 1u);   // round-to-nearest-even
    return (uint16_t)(r >> 16);
}
__device__ __forceinline__ uint32_t pack2bf(float lo, float hi) {
    return (uint32_t)f2bf(lo) | ((uint32_t)f2bf(hi) << 16);
}
__device__ __forceinline__ float bf_lo(uint32_t u) { return __uint_as_float(u << 16); }
__device__ __forceinline__ float bf_hi(uint32_t u) { return __uint_as_float(u & 0xFFFF0000u); }

// ---------------------------------------------------------------------------
// Pass 1 (MFMA, nt=1, x-in-LDS): out = relu(Wf·(x⊙(Wg·s+2bg)) + bf + resid)
// R17 theory (from 9-variant BW table): every global-x-re-read variant is
// pinned at 2.3-2.7 TB/s; both x-from-LDS variants hit 3.1-4.0 TB/s despite
// spill/occupancy pathologies. The 16 scalar x re-loads per thread sit
// serially between GEMM1 and GEMM2 (L2-latency bound, ~2.1GB L2 traffic).
// Fix: ONLY change vs R13 = pack x (bf16) into x_buf during staging (data
// already in registers), acc reads LDS. LDS 36->53KB (3 blocks/CU).
// ---------------------------------------------------------------------------
__global__ void pass1(const float* __restrict__ x, const float* __restrict__ inj0,
                      const float* __restrict__ inj1, const float* __restrict__ resid,
                      const float* __restrict__ gate_w, const float* __restrict__ gate_b,
                      const float* __restrict__ fuse_w, const float* __restrict__ fuse_b,
                      float* __restrict__ out, float* __restrict__ partials)
{
    __shared__ uint32_t s_buf[32 * SSTRIDE];   // 16.9 KB (s / acc / epi tile)
    __shared__ uint32_t x_buf[32 * SSTRIDE];   // 16.9 KB (x bf16 kpairs)
    __shared__ uint32_t w_lds[2][64][36];      // 18.4 KB
    __shared__ float cinit[2][64];             // [0]=2*gate_b, [1]=fuse_b
    __shared__ float wred[16];                 // per-wave stats partials

    const int tid  = threadIdx.x;
    const int lane = tid & 63;
    const int w    = tid >> 6;     // wave 0..7
    const int g    = lane >> 4;    // k-group 0..3
    const int ln   = lane & 15;    // 0..15
    const int n    = 16 * w + ln;  // wave's column within the half

    const int b    = blockIdx.x >> 8;
    const int lb   = blockIdx.x & 255;
    const int bCL  = b * (Cv * Lv);

    // ---- stage weights + cinit (once) ----
    {
        const int mat = tid >> 8;              // 0=gate, 1=fuse
        const int m   = (tid >> 2) & 63;
        const int k0  = (tid & 3) << 4;
        const float* wsrc = mat ? fuse_w : gate_w;
        const float4* w4 = reinterpret_cast<const float4*>(wsrc + m * 64 + k0);
        uint32_t* dst = &w_lds[mat][m][k0 >> 1];
        #pragma unroll
        for (int q = 0; q < 4; ++q) {
            const float4 v = w4[q];
            dst[2 * q]     = pack2bf(v.x, v.y);
            dst[2 * q + 1] = pack2bf(v.z, v.w);
        }
        if (tid < 64) {
            cinit[0][tid] = 2.0f * gate_b[tid];
            cinit[1][tid] = fuse_b[tid];
        }
    }

    float lsum = 0.0f, lsq = 0.0f;

    #pragma unroll 1
    for (int h = 0; h < 2; ++h) {
        const int col0 = lb * COLS + h * HALF;

        // ---- stage s = i0+i1+2x AND x (bf16 kpairs; x reuses loaded regs) --
        #pragma unroll
        for (int uu = 0; uu < 2; ++uu) {
            const int u  = tid + uu * TPB;
            const int kp = u >> 5;               // 0..31 (ch pair)
            const int c  = (u & 31) << 2;        // col 0..124
            const int rA = bCL + (2 * kp) * Lv + col0 + c;
            const int rB = rA + Lv;
            const float4 xA = *reinterpret_cast<const float4*>(x    + rA);
            const float4 aA = *reinterpret_cast<const float4*>(inj0 + rA);
            const float4 bA = *reinterpret_cast<const float4*>(inj1 + rA);
            const float4 xB = *reinterpret_cast<const float4*>(x    + rB);
            const float4 aB = *reinterpret_cast<const float4*>(inj0 + rB);
            const float4 bB = *reinterpret_cast<const float4*>(inj1 + rB);
            uint4 dw;
            dw.x = pack2bf(aA.x + bA.x + 2.0f * xA.x, aB.x + bB.x + 2.0f * xB.x);
            dw.y = pack2bf(aA.y + bA.y + 2.0f * xA.y, aB.y + bB.y + 2.0f * xB.y);
            dw.z = pack2bf(aA.z + bA.z + 2.0f * xA.z, aB.z + bB.z + 2.0f * xB.z);
            dw.w = pack2bf(aA.w + bA.w + 2.0f * xA.w, aB.w + bB.w + 2.0f * xB.w);
            *reinterpret_cast<uint4*>(&s_buf[kp * SSTRIDE + c]) = dw;
            uint4 dx;
            dx.x = pack2bf(xA.x, xB.x);
            dx.y = pack2bf(xA.y, xB.y);
            dx.z = pack2bf(xA.z, xB.z);
            dx.w = pack2bf(xA.w, xB.w);
            *reinterpret_cast<uint4*>(&x_buf[kp * SSTRIDE + c]) = dx;
        }
        __syncthreads();   // s, x (and on h=0: weights/cinit) visible

        // ---- GEMM1: D1 = Wg . s + 2bg  (full K, 8 MFMA, 16 acc regs) ----
        f32x4 D1[4];
        #pragma unroll
        for (int oc = 0; oc < 4; ++oc) {
            const float4 cb = *reinterpret_cast<const float4*>(&cinit[0][16 * oc + 4 * g]);
            D1[oc][0] = cb.x; D1[oc][1] = cb.y; D1[oc][2] = cb.z; D1[oc][3] = cb.w;
        }
        {
            uint4 B0, B1;
            B0.x = s_buf[(4 * g + 0) * SSTRIDE + n];
            B0.y = s_buf[(4 * g + 1) * SSTRIDE + n];
            B0.z = s_buf[(4 * g + 2) * SSTRIDE + n];
            B0.w = s_buf[(4 * g + 3) * SSTRIDE + n];
            B1.x = s_buf[(16 + 4 * g + 0) * SSTRIDE + n];
            B1.y = s_buf[(16 + 4 * g + 1) * SSTRIDE + n];
            B1.z = s_buf[(16 + 4 * g + 2) * SSTRIDE + n];
            B1.w = s_buf[(16 + 4 * g + 3) * SSTRIDE + n];
            #pragma unroll
            for (int oc = 0; oc < 4; ++oc) {
                const int m = ln + 16 * oc;
                const uint4 A0 = *reinterpret_cast<const uint4*>(&w_lds[0][m][4 * g]);
                const uint4 A1 = *reinterpret_cast<const uint4*>(&w_lds[0][m][16 + 4 * g]);
                D1[oc] = __builtin_amdgcn_mfma_f32_16x16x32_bf16(
                    __builtin_bit_cast(short8, A0), __builtin_bit_cast(short8, B0),
                    D1[oc], 0, 0, 0);
                D1[oc] = __builtin_amdgcn_mfma_f32_16x16x32_bf16(
                    __builtin_bit_cast(short8, A1), __builtin_bit_cast(short8, B1),
                    D1[oc], 0, 0, 0);
            }
        }

        // ---- acc = x*g (x from LDS) -> in-place into s_buf (own slab) ----
        #pragma unroll
        for (int oc = 0; oc < 4; ++oc) {
            const int kp = 8 * oc + 2 * g;            // ch pair (16oc+4g)/2
            const uint32_t u0 = x_buf[kp * SSTRIDE + n];
            const uint32_t u1 = x_buf[(kp + 1) * SSTRIDE + n];
            float av[4];
            av[0] = bf_lo(u0) * D1[oc][0];
            av[1] = bf_hi(u0) * D1[oc][1];
            av[2] = bf_lo(u1) * D1[oc][2];
            av[3] = bf_hi(u1) * D1[oc][3];
            s_buf[kp * SSTRIDE + n]       = pack2bf(av[0], av[1]);
            s_buf[(kp + 1) * SSTRIDE + n] = pack2bf(av[2], av[3]);
        }
        __syncthreads();   // same-slab ordering safety (as R13)

        // ---- GEMM2: D2 = Wf . acc + fuse_b  (full K, 8 MFMA, 16 acc regs) --
        f32x4 D2[4];
        #pragma unroll
        for (int oc = 0; oc < 4; ++oc) {
            const float4 cb = *reinterpret_cast<const float4*>(&cinit[1][16 * oc + 4 * g]);
            D2[oc][0] = cb.x; D2[oc][1] = cb.y; D2[oc][2] = cb.z; D2[oc][3] = cb.w;
        }
        {
            uint4 B0, B1;
            B0.x = s_buf[(4 * g + 0) * SSTRIDE + n];
            B0.y = s_buf[(4 * g + 1) * SSTRIDE + n];
            B0.z = s_buf[(4 * g + 2) * SSTRIDE + n];
            B0.w = s_buf[(4 * g + 3) * SSTRIDE + n];
            B1.x = s_buf[(16 + 4 * g + 0) * SSTRIDE + n];
            B1.y = s_buf[(16 + 4 * g + 1) * SSTRIDE + n];
            B1.z = s_buf[(16 + 4 * g + 2) * SSTRIDE + n];
            B1.w = s_buf[(16 + 4 * g + 3) * SSTRIDE + n];
            #pragma unroll
            for (int oc = 0; oc < 4; ++oc) {
                const int m = ln + 16 * oc;
                const uint4 A0 = *reinterpret_cast<const uint4*>(&w_lds[1][m][4 * g]);
                const uint4 A1 = *reinterpret_cast<const uint4*>(&w_lds[1][m][16 + 4 * g]);
                D2[oc] = __builtin_amdgcn_mfma_f32_16x16x32_bf16(
                    __builtin_bit_cast(short8, A0), __builtin_bit_cast(short8, B0),
                    D2[oc], 0, 0, 0);
                D2[oc] = __builtin_amdgcn_mfma_f32_16x16x32_bf16(
                    __builtin_bit_cast(short8, A1), __builtin_bit_cast(short8, B1),
                    D2[oc], 0, 0, 0);
            }
        }
        __syncthreads();   // GEMM2 B-reads done before epi overwrites s_buf

        // ---- epilogue: 2 chunks of 32 rows via s_buf re-layout ----
        {
            float* uf = reinterpret_cast<float*>(s_buf);
            const int rowin = tid >> 4;          // 0..31
            const int cl    = tid & 15;          // 16 threads x 2 float4 per row
            #pragma unroll 1
            for (int ck = 0; ck < 2; ++ck) {
                #pragma unroll
                for (int oc2 = 0; oc2 < 2; ++oc2) {
                    const int oc = 2 * ck + oc2;
                    #pragma unroll
                    for (int j = 0; j < 4; ++j)
                        uf[(16 * oc2 + 4 * g + j) * SSTRIDE + n] = D2[oc][j];
                }
                const int m   = 32 * ck + rowin;
                const int gbm = bCL + m * Lv + col0;
                const float4 ra = *reinterpret_cast<const float4*>(&resid[gbm + 4 * cl]);
                const float4 rb = *reinterpret_cast<const float4*>(&resid[gbm + 4 * cl + 64]);
                __syncthreads();
                float4 va = *reinterpret_cast<const float4*>(&uf[rowin * SSTRIDE + 4 * cl]);
                float4 vb = *reinterpret_cast<const float4*>(&uf[rowin * SSTRIDE + 4 * cl + 64]);
                va.x = fmaxf(va.x + ra.x, 0.0f); va.y = fmaxf(va.y + ra.y, 0.0f);
                va.z = fmaxf(va.z + ra.z, 0.0f); va.w = fmaxf(va.w + ra.w, 0.0f);
                vb.x = fmaxf(vb.x + rb.x, 0.0f); vb.y = fmaxf(vb.y + rb.y, 0.0f);
                vb.z = fmaxf(vb.z + rb.z, 0.0f); vb.w = fmaxf(vb.w + rb.w, 0.0f);
                *reinterpret_cast<float4*>(&out[gbm + 4 * cl])      = va;
                *reinterpret_cast<float4*>(&out[gbm + 4 * cl + 64]) = vb;
                lsum += (va.x + va.y) + (va.z + va.w) + (vb.x + vb.y) + (vb.z + vb.w);
                lsq = fmaf(va.x, va.x, lsq); lsq = fmaf(va.y, va.y, lsq);
                lsq = fmaf(va.z, va.z, lsq); lsq = fmaf(va.w, va.w, lsq);
                lsq = fmaf(vb.x, vb.x, lsq); lsq = fmaf(vb.y, vb.y, lsq);
                lsq = fmaf(vb.z, vb.z, lsq); lsq = fmaf(vb.w, vb.w, lsq);
                __syncthreads();   // chunk reads done before next writes
            }
        }
    }

    // ---- stats: wave shuffle reduce -> 8 partials -> thread 0 ----
    #pragma unroll
    for (int st = 1; st < 64; st <<= 1) {
        lsum += __shfl_xor(lsum, st);
        lsq  += __shfl_xor(lsq,  st);
    }
    if (lane == 0) { wred[2 * w] = lsum; wred[2 * w + 1] = lsq; }
    __syncthreads();
    if (tid == 0) {
        float s = 0.0f, q = 0.0f;
        #pragma unroll
        for (int i = 0; i < 8; ++i) { s += wred[2 * i]; q += wred[2 * i + 1]; }
        partials[2 * blockIdx.x]     = s;
        partials[2 * blockIdx.x + 1] = q;
    }
}

// ---------------------------------------------------------------------------
// Pass 2: reduce 256 partials per batch -> per-(b,c) scale/bias.
// ---------------------------------------------------------------------------
__global__ __launch_bounds__(256)
void pass2(const float* __restrict__ partials, const float* __restrict__ gn_w,
           const float* __restrict__ gn_b, float* __restrict__ sb)
{
    __shared__ float r1[256], r2[256];
    __shared__ float mean_s, rs_s;
    const int b = blockIdx.x, tid = threadIdx.x;
    r1[tid] = partials[2 * (b * 256 + tid)];
    r2[tid] = partials[2 * (b * 256 + tid) + 1];
    __syncthreads();
    #pragma unroll
    for (int st = 128; st > 0; st >>= 1) {
        if (tid < st) { r1[tid] += r1[tid + st]; r2[tid] += r2[tid + st]; }
        __syncthreads();
    }
    if (tid == 0) {
        const float n = (float)Cv * (float)Lv;
        const float mean = r1[0] / n;
        const float var  = r2[0] / n - mean * mean;
        mean_s = mean;
        rs_s   = rsqrtf(var + 1e-5f);
    }
    __syncthreads();
    if (tid < Cv) {
        const float sc = gn_w[tid] * rs_s;
        sb[b * Cv + tid]           = sc;
        sb[Bv * Cv + b * Cv + tid] = fmaf(-mean_s, sc, gn_b[tid]);
    }
}

// ---------------------------------------------------------------------------
// Pass 3: in-place GroupNorm affine on d_out (float4 vectorized).
// ---------------------------------------------------------------------------
__global__ __launch_bounds__(256)
void pass3(float* __restrict__ out, const float* __restrict__ sb)
{
    const int total4 = (Bv * Cv * Lv) / 4;   // 8388608
    for (int i = blockIdx.x * blockDim.x + threadIdx.x; i < total4;
         i += gridDim.x * blockDim.x) {
        const int row = i >> 14;            // / (L/4): row = b*64 + c
        const float sc = sb[row];
        const float bi = sb[Bv * Cv + row];
        float4 v = reinterpret_cast<float4*>(out)[i];
        v.x = fmaf(v.x, sc, bi);
        v.y = fmaf(v.y, sc, bi);
        v.z = fmaf(v.z, sc, bi);
        v.w = fmaf(v.w, sc, bi);
        reinterpret_cast<float4*>(out)[i] = v;
    }
}

extern "C" void kernel_launch(void* const* d_in, const int* in_sizes, int n_in,
                              void* d_out, int out_size, void* d_ws, size_t ws_size,
                              hipStream_t stream)
{
    const float* x      = (const float*)d_in[0];
    const float* inj0   = (const float*)d_in[1];
    const float* inj1   = (const float*)d_in[2];
    const float* resid  = (const float*)d_in[3];
    const float* gate_w = (const float*)d_in[4];
    const float* gate_b = (const float*)d_in[5];
    const float* fuse_w = (const float*)d_in[6];
    const float* fuse_b = (const float*)d_in[7];
    const float* gn_w   = (const float*)d_in[8];
    const float* gn_b   = (const float*)d_in[9];

    float* out      = (float*)d_out;
    float* ws       = (float*)d_ws;
    float* partials = ws;                 // 2 * 2048 floats = 16 KiB
    float* sb       = ws + 2 * GRID1;     // 2 * 512 floats  =  4 KiB

    hipLaunchKernelGGL(pass1, dim3(GRID1), dim3(TPB), 0, stream,
                       x, inj0, inj1, resid, gate_w, gate_b, fuse_w, fuse_b,
                       out, partials);
    hipLaunchKernelGGL(pass2, dim3(Bv), dim3(256), 0, stream,
                       partials, gn_w, gn_b, sb);
    hipLaunchKernelGGL(pass3, dim3(2048), dim3(256), 0, stream, out, sb);
}